// Round 2
// baseline (1642.007 us; speedup 1.0000x reference)
//
#include <hip/hip_runtime.h>
#include <hip/hip_bf16.h>
#include <cstdint>
#include <cstddef>

// QRNN encoder, 3 layers. T=512 B=64 E=300 H=800.
// Chunked pipeline (4 chunks of T_C=128): per chunk, per layer:
//   bf16 MFMA GEMM (A[8192,K] x Wt[N,K]) + fused bias/act -> bf16 gates ZFO
//   -> fo-pool scan chunk (fp32 carry in small buffer) -> h chunk (bf16).
// Workspace ~81 MB (prior 402 MB design aborted: ws OOB).

typedef __bf16 bf16_t;
typedef __bf16 bf16x8 __attribute__((ext_vector_type(8)));
typedef float f32x4 __attribute__((ext_vector_type(4)));

#define T_SEQ 512
#define T_C 128
#define NCHUNK 4
#define BATCH 64
#define EMB 300
#define HID 800
#define LDG 2432                // 3H=2400 padded to 19*128
#define MC (T_C * BATCH)        // 8192 rows per chunk

__device__ __forceinline__ float fast_sigmoid(float x) {
  return 1.0f / (1.0f + __expf(-x));
}
__device__ __forceinline__ float fast_tanh(float x) {
  return 2.0f / (1.0f + __expf(-2.0f * x)) - 1.0f;
}

// ---- prep: cast sent chunk [8192,300] fp32 -> bf16 [8192,320] (zero-pad K) ----
__global__ __launch_bounds__(256) void cast_pad_a0(const float* __restrict__ X,
                                                   bf16_t* __restrict__ Y) {
  int idx = blockIdx.x * 256 + threadIdx.x;
  if (idx >= MC * 320) return;
  int r = idx / 320, c = idx - r * 320;
  float v = (c < EMB) ? X[(size_t)r * EMB + c] : 0.0f;
  Y[idx] = (bf16_t)v;
}

// ---- prep: W [K,N] fp32 -> Wt [2432,Kpad] bf16 (transposed, zero-pad) ----
__global__ __launch_bounds__(256) void transpose_cast_w(const float* __restrict__ W,
                                                        bf16_t* __restrict__ Wt,
                                                        int K, int N, int Kpad) {
  __shared__ float tile[32][33];
  int i = blockIdx.x;  // n tile
  int j = blockIdx.y;  // k tile
  int tx = threadIdx.x & 31, ty = threadIdx.x >> 5;
#pragma unroll
  for (int r = 0; r < 32; r += 8) {
    int k = j * 32 + ty + r, n = i * 32 + tx;
    tile[ty + r][tx] = (k < K && n < N) ? W[(size_t)k * N + n] : 0.0f;
  }
  __syncthreads();
#pragma unroll
  for (int r = 0; r < 32; r += 8) {
    int n = i * 32 + ty + r, k = j * 32 + tx;
    Wt[(size_t)n * Kpad + k] = (bf16_t)tile[tx][ty + r];
  }
}

// ---- async 16B global->LDS (wave-uniform base + lane*16 layout) ----
__device__ __forceinline__ void stage16(const bf16_t* gp, bf16_t* lp) {
  __builtin_amdgcn_global_load_lds((__attribute__((address_space(1))) void*)gp,
                                   (__attribute__((address_space(3))) void*)lp,
                                   16, 0, 0);
}

// ---- bf16 MFMA GEMM, 128x128 tile, BK=32, fused bias+activation, bf16 out ----
// A [8192,K] row-major bf16 (16|K), Bt [2432,K] row-major bf16.
// G[row,col] = act(A@Bt^T + bias): col<800 tanh, col<2400 sigmoid.
__global__ __launch_bounds__(256) void gemm_act(const bf16_t* __restrict__ A,
                                                const bf16_t* __restrict__ Bt,
                                                const float* __restrict__ bias,
                                                bf16_t* __restrict__ G,
                                                int K) {
  __shared__ __align__(16) bf16_t As[128 * 32];
  __shared__ __align__(16) bf16_t Bs[128 * 32];
  const int tid = threadIdx.x;
  const int wave = tid >> 6, lane = tid & 63;
  const int wm = wave >> 1, wn = wave & 1;  // 2x2 waves of 64x64
  const int mBase = blockIdx.y * 128;
  const int nBase = blockIdx.x * 128;

  const int rowA = tid >> 2, cq = tid & 3;  // 16B chunk per thread
  const size_t aOff0 = (size_t)(mBase + rowA) * K + cq * 8;
  const size_t aOff1 = (size_t)(mBase + 64 + rowA) * K + cq * 8;
  const size_t bOff0 = (size_t)(nBase + rowA) * K + cq * 8;
  const size_t bOff1 = (size_t)(nBase + 64 + rowA) * K + cq * 8;

  f32x4 acc[4][4];
#pragma unroll
  for (int mt = 0; mt < 4; ++mt)
#pragma unroll
    for (int nt = 0; nt < 4; ++nt) {
      f32x4 z = {0.0f, 0.0f, 0.0f, 0.0f};
      acc[mt][nt] = z;
    }

  const int fr = lane & 15, fq = lane >> 4;

  for (int k0 = 0; k0 < K; k0 += 32) {
    stage16(A + aOff0 + k0, &As[tid * 8]);
    stage16(A + aOff1 + k0, &As[2048 + tid * 8]);
    stage16(Bt + bOff0 + k0, &Bs[tid * 8]);
    stage16(Bt + bOff1 + k0, &Bs[2048 + tid * 8]);
    __syncthreads();

    bf16x8 af[4], bfv[4];
#pragma unroll
    for (int mt = 0; mt < 4; ++mt)
      af[mt] = *(const bf16x8*)&As[(wm * 64 + mt * 16 + fr) * 32 + fq * 8];
#pragma unroll
    for (int nt = 0; nt < 4; ++nt)
      bfv[nt] = *(const bf16x8*)&Bs[(wn * 64 + nt * 16 + fr) * 32 + fq * 8];
#pragma unroll
    for (int mt = 0; mt < 4; ++mt)
#pragma unroll
      for (int nt = 0; nt < 4; ++nt)
        acc[mt][nt] = __builtin_amdgcn_mfma_f32_16x16x32_bf16(
            af[mt], bfv[nt], acc[mt][nt], 0, 0, 0);
    __syncthreads();
  }

  // epilogue: C/D layout col=lane&15, row=(lane>>4)*4+r
#pragma unroll
  for (int nt = 0; nt < 4; ++nt) {
    const int tbase = nBase + wn * 64 + nt * 16;
    const int gcol = tbase + fr;
    const float bv = (gcol < 2400) ? bias[gcol] : 0.0f;
#pragma unroll
    for (int mt = 0; mt < 4; ++mt) {
#pragma unroll
      for (int r = 0; r < 4; ++r) {
        const int grow = mBase + wm * 64 + mt * 16 + fq * 4 + r;
        float v = acc[mt][nt][r] + bv;
        if (tbase < 800)
          v = fast_tanh(v);
        else if (tbase < 2400)
          v = fast_sigmoid(v);
        G[(size_t)grow * LDG + gcol] = (bf16_t)v;
      }
    }
  }
}

// ---- fo-pool scan over one T-chunk, one thread per (b,h), PF=8 prefetch ----
// G bf16 gates: z' at col h, f' at h+800, o' at h+1600. carry[b*H+h] fp32.
__global__ __launch_bounds__(256) void scan_chunk(const bf16_t* __restrict__ G,
                                                  bf16_t* __restrict__ Hout,
                                                  float* __restrict__ carry,
                                                  float* __restrict__ outC,
                                                  int outOff, int writeH,
                                                  int first, int last) {
  const int idx = blockIdx.x * 256 + threadIdx.x;  // 0..51199
  const int b = idx / HID;
  const int h = idx - b * HID;

  float zb[8], fb[8], ob[8];
#pragma unroll
  for (int i = 0; i < 8; ++i) {
    size_t base = (size_t)(i * BATCH + b) * LDG + h;
    zb[i] = (float)G[base];
    fb[i] = (float)G[base + 800];
    ob[i] = writeH ? (float)G[base + 1600] : 0.0f;
  }
  float c = first ? 0.0f : carry[idx];
  for (int t0 = 0; t0 < T_C; t0 += 8) {
#pragma unroll
    for (int i = 0; i < 8; ++i) {
      const int t = t0 + i;
      const float z = zb[i], f = fb[i], o = ob[i];
      const int tp = t + 8;
      if (tp < T_C) {
        size_t base = (size_t)(tp * BATCH + b) * LDG + h;
        zb[i] = (float)G[base];
        fb[i] = (float)G[base + 800];
        if (writeH) ob[i] = (float)G[base + 1600];
      }
      c = fmaf(f, z - c, c);  // f*z + (1-f)*c
      if (writeH) Hout[(size_t)(t * BATCH + b) * HID + h] = (bf16_t)(o * c);
    }
  }
  carry[idx] = c;
  if (last) outC[b * 2400 + outOff + h] = c;
}

extern "C" void kernel_launch(void* const* d_in, const int* in_sizes, int n_in,
                              void* d_out, int out_size, void* d_ws, size_t ws_size,
                              hipStream_t stream) {
  const float* sent = (const float*)d_in[0];
  // d_in[1] = lengths: unused by the reference
  const float* W0 = (const float*)d_in[2];
  const float* b0 = (const float*)d_in[3];
  const float* W1 = (const float*)d_in[4];
  const float* b1 = (const float*)d_in[5];
  const float* W2 = (const float*)d_in[6];
  const float* b2 = (const float*)d_in[7];
  float* out = (float*)d_out;

  char* ws = (char*)d_ws;
  size_t off = 0;
  auto alloc = [&](size_t bytes) {
    void* p = ws + off;
    off += (bytes + 255) & ~(size_t)255;
    return p;
  };
  bf16_t* W0t = (bf16_t*)alloc((size_t)2432 * 320 * 2);  // 1.6 MB
  bf16_t* W1t = (bf16_t*)alloc((size_t)2432 * 800 * 2);  // 3.9 MB
  bf16_t* W2t = (bf16_t*)alloc((size_t)2432 * 800 * 2);  // 3.9 MB
  bf16_t* A0c = (bf16_t*)alloc((size_t)MC * 320 * 2);    // 5.2 MB
  bf16_t* H0c = (bf16_t*)alloc((size_t)MC * HID * 2);    // 13.1 MB
  bf16_t* H1c = (bf16_t*)alloc((size_t)MC * HID * 2);    // 13.1 MB
  bf16_t* ZFO = (bf16_t*)alloc((size_t)MC * LDG * 2);    // 39.8 MB
  float* C0 = (float*)alloc((size_t)BATCH * HID * 4);    // 205 KB
  float* C1 = (float*)alloc((size_t)BATCH * HID * 4);
  float* C2 = (float*)alloc((size_t)BATCH * HID * 4);
  if (off > ws_size) return;  // ws too small: fail verification, don't fault

  transpose_cast_w<<<dim3(76, 10), 256, 0, stream>>>(W0, W0t, 300, 2400, 320);
  transpose_cast_w<<<dim3(76, 25), 256, 0, stream>>>(W1, W1t, 800, 2400, 800);
  transpose_cast_w<<<dim3(76, 25), 256, 0, stream>>>(W2, W2t, 800, 2400, 800);

  for (int c = 0; c < NCHUNK; ++c) {
    const int first = (c == 0), last = (c == NCHUNK - 1);
    // layer 0
    cast_pad_a0<<<(MC * 320 + 255) / 256, 256, 0, stream>>>(
        sent + (size_t)c * MC * EMB, A0c);
    gemm_act<<<dim3(19, 64), 256, 0, stream>>>(A0c, W0t, b0, ZFO, 320);
    scan_chunk<<<200, 256, 0, stream>>>(ZFO, H0c, C0, out, 0, 1, first, last);
    // layer 1
    gemm_act<<<dim3(19, 64), 256, 0, stream>>>(H0c, W1t, b1, ZFO, 800);
    scan_chunk<<<200, 256, 0, stream>>>(ZFO, H1c, C1, out, 800, 1, first, last);
    // layer 2: o-gate dead (only c_last needed) -> 13 col tiles (N=1664)
    gemm_act<<<dim3(13, 64), 256, 0, stream>>>(H1c, W2t, b2, ZFO, 800);
    scan_chunk<<<200, 256, 0, stream>>>(ZFO, nullptr, C2, out, 1600, 0, first, last);
  }
}

// Round 3
// 949.534 us; speedup vs baseline: 1.7293x; 1.7293x over previous
//
#include <hip/hip_runtime.h>
#include <hip/hip_bf16.h>
#include <cstdint>
#include <cstddef>

// QRNN encoder, 3 layers. T=512 B=64 E=300 H=800.
// Chunked pipeline (4 chunks of T_C=128): per chunk, per layer:
//   bf16 MFMA GEMM (A[8192,K] x Wt[N,K]) + fused bias/act -> bf16 gates ZFO
//   -> segment-parallel fo-pool scan (8 segs x 16 steps, affine-map combine)
//   -> h chunk (bf16). Workspace ~81 MB.

typedef __bf16 bf16_t;
typedef __bf16 bf16x8 __attribute__((ext_vector_type(8)));
typedef float f32x4 __attribute__((ext_vector_type(4)));

#define T_SEQ 512
#define T_C 128
#define NCHUNK 4
#define BATCH 64
#define EMB 300
#define HID 800
#define LDG 2432                // 3H=2400 padded to 19*128
#define MC (T_C * BATCH)        // 8192 rows per chunk

__device__ __forceinline__ float fast_sigmoid(float x) {
  return 1.0f / (1.0f + __expf(-x));
}
__device__ __forceinline__ float fast_tanh(float x) {
  return 2.0f / (1.0f + __expf(-2.0f * x)) - 1.0f;
}

// ---- prep: cast sent chunk [8192,300] fp32 -> bf16 [8192,320] (zero-pad K) ----
__global__ __launch_bounds__(256) void cast_pad_a0(const float* __restrict__ X,
                                                   bf16_t* __restrict__ Y) {
  int idx = blockIdx.x * 256 + threadIdx.x;
  if (idx >= MC * 320) return;
  int r = idx / 320, c = idx - r * 320;
  float v = (c < EMB) ? X[(size_t)r * EMB + c] : 0.0f;
  Y[idx] = (bf16_t)v;
}

// ---- prep: W [K,N] fp32 -> Wt [2432,Kpad] bf16 (transposed, zero-pad) ----
__global__ __launch_bounds__(256) void transpose_cast_w(const float* __restrict__ W,
                                                        bf16_t* __restrict__ Wt,
                                                        int K, int N, int Kpad) {
  __shared__ float tile[32][33];
  int i = blockIdx.x;  // n tile
  int j = blockIdx.y;  // k tile
  int tx = threadIdx.x & 31, ty = threadIdx.x >> 5;
#pragma unroll
  for (int r = 0; r < 32; r += 8) {
    int k = j * 32 + ty + r, n = i * 32 + tx;
    tile[ty + r][tx] = (k < K && n < N) ? W[(size_t)k * N + n] : 0.0f;
  }
  __syncthreads();
#pragma unroll
  for (int r = 0; r < 32; r += 8) {
    int n = i * 32 + ty + r, k = j * 32 + tx;
    Wt[(size_t)n * Kpad + k] = (bf16_t)tile[tx][ty + r];
  }
}

// ---- async 16B global->LDS (wave-uniform base + lane*16 layout) ----
__device__ __forceinline__ void stage16(const bf16_t* gp, bf16_t* lp) {
  __builtin_amdgcn_global_load_lds((__attribute__((address_space(1))) void*)gp,
                                   (__attribute__((address_space(3))) void*)lp,
                                   16, 0, 0);
}

// ---- bf16 MFMA GEMM, 128x128 tile, BK=32, fused bias+activation, bf16 out ----
// A [8192,K] row-major bf16 (16|K), Bt [2432,K] row-major bf16.
// G[row,col] = act(A@Bt^T + bias): col<800 tanh, col<2400 sigmoid.
__global__ __launch_bounds__(256) void gemm_act(const bf16_t* __restrict__ A,
                                                const bf16_t* __restrict__ Bt,
                                                const float* __restrict__ bias,
                                                bf16_t* __restrict__ G,
                                                int K) {
  __shared__ __align__(16) bf16_t As[128 * 32];
  __shared__ __align__(16) bf16_t Bs[128 * 32];
  const int tid = threadIdx.x;
  const int wave = tid >> 6, lane = tid & 63;
  const int wm = wave >> 1, wn = wave & 1;  // 2x2 waves of 64x64
  const int mBase = blockIdx.y * 128;
  const int nBase = blockIdx.x * 128;

  const int rowA = tid >> 2, cq = tid & 3;  // 16B chunk per thread
  const size_t aOff0 = (size_t)(mBase + rowA) * K + cq * 8;
  const size_t aOff1 = (size_t)(mBase + 64 + rowA) * K + cq * 8;
  const size_t bOff0 = (size_t)(nBase + rowA) * K + cq * 8;
  const size_t bOff1 = (size_t)(nBase + 64 + rowA) * K + cq * 8;

  f32x4 acc[4][4];
#pragma unroll
  for (int mt = 0; mt < 4; ++mt)
#pragma unroll
    for (int nt = 0; nt < 4; ++nt) {
      f32x4 z = {0.0f, 0.0f, 0.0f, 0.0f};
      acc[mt][nt] = z;
    }

  const int fr = lane & 15, fq = lane >> 4;

  for (int k0 = 0; k0 < K; k0 += 32) {
    stage16(A + aOff0 + k0, &As[tid * 8]);
    stage16(A + aOff1 + k0, &As[2048 + tid * 8]);
    stage16(Bt + bOff0 + k0, &Bs[tid * 8]);
    stage16(Bt + bOff1 + k0, &Bs[2048 + tid * 8]);
    __syncthreads();

    bf16x8 af[4], bfv[4];
#pragma unroll
    for (int mt = 0; mt < 4; ++mt)
      af[mt] = *(const bf16x8*)&As[(wm * 64 + mt * 16 + fr) * 32 + fq * 8];
#pragma unroll
    for (int nt = 0; nt < 4; ++nt)
      bfv[nt] = *(const bf16x8*)&Bs[(wn * 64 + nt * 16 + fr) * 32 + fq * 8];
#pragma unroll
    for (int mt = 0; mt < 4; ++mt)
#pragma unroll
      for (int nt = 0; nt < 4; ++nt)
        acc[mt][nt] = __builtin_amdgcn_mfma_f32_16x16x32_bf16(
            af[mt], bfv[nt], acc[mt][nt], 0, 0, 0);
    __syncthreads();
  }

  // epilogue: C/D layout col=lane&15, row=(lane>>4)*4+r
#pragma unroll
  for (int nt = 0; nt < 4; ++nt) {
    const int tbase = nBase + wn * 64 + nt * 16;
    const int gcol = tbase + fr;
    const float bv = (gcol < 2400) ? bias[gcol] : 0.0f;
#pragma unroll
    for (int mt = 0; mt < 4; ++mt) {
#pragma unroll
      for (int r = 0; r < 4; ++r) {
        const int grow = mBase + wm * 64 + mt * 16 + fq * 4 + r;
        float v = acc[mt][nt][r] + bv;
        if (tbase < 800)
          v = fast_tanh(v);
        else if (tbase < 2400)
          v = fast_sigmoid(v);
        G[(size_t)grow * LDG + gcol] = (bf16_t)v;
      }
    }
  }
}

// ---- segment-parallel fo-pool scan over one T-chunk ----
// Thread (chain, seg): seg handles 16 timesteps. c_t = a_t c_{t-1} + b_t with
// a=1-f, b=f*z. Phase 1: compose (A,B) per segment, gates kept in registers.
// Phase 2: 32 serial combiners (one per chain in block) via LDS.
// Phase 3: rescan from incoming carry, h_t = o_t * c_t (skipped if !writeH).
__global__ __launch_bounds__(256) void scan_chunk_seg(
    const bf16_t* __restrict__ G, bf16_t* __restrict__ Hout,
    float* __restrict__ carry, float* __restrict__ outC,
    int outOff, int writeH, int first, int last) {
  __shared__ float SA[8][32], SB[8][32], SC[8][32];
  const int chainLane = threadIdx.x & 31;
  const int seg = threadIdx.x >> 5;
  const int ch = blockIdx.x * 32 + chainLane;  // 0..51199
  const int b = ch / HID, h = ch - b * HID;
  const int t0 = seg * 16;

  float zr[16], fv[16];
#pragma unroll
  for (int j = 0; j < 16; ++j) {
    size_t base = (size_t)((t0 + j) * BATCH + b) * LDG + h;
    zr[j] = (float)G[base];
    fv[j] = (float)G[base + 800];
  }
  float A = 1.0f, Bacc = 0.0f;
#pragma unroll
  for (int j = 0; j < 16; ++j) {
    const float a = 1.0f - fv[j];
    A *= a;
    Bacc = fmaf(a, Bacc, fv[j] * zr[j]);
  }
  SA[seg][chainLane] = A;
  SB[seg][chainLane] = Bacc;
  __syncthreads();
  if (threadIdx.x < 32) {
    const int cc = blockIdx.x * 32 + threadIdx.x;
    float c = first ? 0.0f : carry[cc];
#pragma unroll
    for (int s = 0; s < 8; ++s) {
      SC[s][threadIdx.x] = c;
      c = fmaf(SA[s][threadIdx.x], c, SB[s][threadIdx.x]);
    }
    carry[cc] = c;
    if (last) {
      const int b2 = cc / HID, h2 = cc - b2 * HID;
      outC[b2 * 2400 + outOff + h2] = c;
    }
  }
  __syncthreads();
  if (!writeH) return;
  float c = SC[seg][chainLane];
#pragma unroll
  for (int j = 0; j < 16; ++j) {
    const size_t row = (size_t)((t0 + j) * BATCH + b);
    const float o = (float)G[row * LDG + h + 1600];
    c = fmaf(fv[j], zr[j] - c, c);  // f*z + (1-f)*c
    Hout[row * HID + h] = (bf16_t)(o * c);
  }
}

extern "C" void kernel_launch(void* const* d_in, const int* in_sizes, int n_in,
                              void* d_out, int out_size, void* d_ws, size_t ws_size,
                              hipStream_t stream) {
  const float* sent = (const float*)d_in[0];
  // d_in[1] = lengths: unused by the reference
  const float* W0 = (const float*)d_in[2];
  const float* b0 = (const float*)d_in[3];
  const float* W1 = (const float*)d_in[4];
  const float* b1 = (const float*)d_in[5];
  const float* W2 = (const float*)d_in[6];
  const float* b2 = (const float*)d_in[7];
  float* out = (float*)d_out;

  char* ws = (char*)d_ws;
  size_t off = 0;
  auto alloc = [&](size_t bytes) {
    void* p = ws + off;
    off += (bytes + 255) & ~(size_t)255;
    return p;
  };
  bf16_t* W0t = (bf16_t*)alloc((size_t)2432 * 320 * 2);  // 1.6 MB
  bf16_t* W1t = (bf16_t*)alloc((size_t)2432 * 800 * 2);  // 3.9 MB
  bf16_t* W2t = (bf16_t*)alloc((size_t)2432 * 800 * 2);  // 3.9 MB
  bf16_t* A0c = (bf16_t*)alloc((size_t)MC * 320 * 2);    // 5.2 MB
  bf16_t* H0c = (bf16_t*)alloc((size_t)MC * HID * 2);    // 13.1 MB
  bf16_t* H1c = (bf16_t*)alloc((size_t)MC * HID * 2);    // 13.1 MB
  bf16_t* ZFO = (bf16_t*)alloc((size_t)MC * LDG * 2);    // 39.8 MB
  float* C0 = (float*)alloc((size_t)BATCH * HID * 4);    // 205 KB
  float* C1 = (float*)alloc((size_t)BATCH * HID * 4);
  float* C2 = (float*)alloc((size_t)BATCH * HID * 4);
  if (off > ws_size) return;  // ws too small: fail verification, don't fault

  transpose_cast_w<<<dim3(76, 10), 256, 0, stream>>>(W0, W0t, 300, 2400, 320);
  transpose_cast_w<<<dim3(76, 25), 256, 0, stream>>>(W1, W1t, 800, 2400, 800);
  transpose_cast_w<<<dim3(76, 25), 256, 0, stream>>>(W2, W2t, 800, 2400, 800);

  for (int c = 0; c < NCHUNK; ++c) {
    const int first = (c == 0), last = (c == NCHUNK - 1);
    // layer 0
    cast_pad_a0<<<(MC * 320 + 255) / 256, 256, 0, stream>>>(
        sent + (size_t)c * MC * EMB, A0c);
    gemm_act<<<dim3(19, 64), 256, 0, stream>>>(A0c, W0t, b0, ZFO, 320);
    scan_chunk_seg<<<1600, 256, 0, stream>>>(ZFO, H0c, C0, out, 0, 1, first, last);
    // layer 1
    gemm_act<<<dim3(19, 64), 256, 0, stream>>>(H0c, W1t, b1, ZFO, 800);
    scan_chunk_seg<<<1600, 256, 0, stream>>>(ZFO, H1c, C1, out, 800, 1, first, last);
    // layer 2: o-gate dead (only c_last needed) -> 13 col tiles (N=1664)
    gemm_act<<<dim3(13, 64), 256, 0, stream>>>(H1c, W2t, b2, ZFO, 800);
    scan_chunk_seg<<<1600, 256, 0, stream>>>(ZFO, nullptr, C2, out, 1600, 0, first, last);
  }
}

// Round 4
// 879.590 us; speedup vs baseline: 1.8668x; 1.0795x over previous
//
#include <hip/hip_runtime.h>
#include <hip/hip_bf16.h>
#include <cstdint>
#include <cstddef>

// QRNN encoder, 3 layers. T=512 B=64 E=300 H=800.
// Chunked pipeline (4 chunks of T_C=128): per chunk, per layer:
//   bf16 MFMA GEMM (pure matmul, raw bf16 gates out, coalesced stores via
//   LDS transpose) -> segment-parallel fo-pool scan applying bias+activation
//   in fp32 -> h chunk (bf16). Workspace ~81 MB.

typedef __bf16 bf16_t;
typedef __bf16 bf16x8 __attribute__((ext_vector_type(8)));
typedef float f32x4 __attribute__((ext_vector_type(4)));

#define T_SEQ 512
#define T_C 128
#define NCHUNK 4
#define BATCH 64
#define EMB 300
#define HID 800
#define LDG 2432                // 3H=2400 padded to 19*128
#define MC (T_C * BATCH)        // 8192 rows per chunk

__device__ __forceinline__ float fast_sigmoid(float x) {
  return 1.0f / (1.0f + __expf(-x));
}
__device__ __forceinline__ float fast_tanh(float x) {
  return 2.0f / (1.0f + __expf(-2.0f * x)) - 1.0f;
}

// ---- prep: cast sent chunk [8192,300] fp32 -> bf16 [8192,320] (zero-pad K) ----
__global__ __launch_bounds__(256) void cast_pad_a0(const float* __restrict__ X,
                                                   bf16_t* __restrict__ Y) {
  int idx = blockIdx.x * 256 + threadIdx.x;
  if (idx >= MC * 320) return;
  int r = idx / 320, c = idx - r * 320;
  float v = (c < EMB) ? X[(size_t)r * EMB + c] : 0.0f;
  Y[idx] = (bf16_t)v;
}

// ---- prep: W [K,N] fp32 -> Wt [2432,Kpad] bf16 (transposed, zero-pad) ----
__global__ __launch_bounds__(256) void transpose_cast_w(const float* __restrict__ W,
                                                        bf16_t* __restrict__ Wt,
                                                        int K, int N, int Kpad) {
  __shared__ float tile[32][33];
  int i = blockIdx.x;  // n tile
  int j = blockIdx.y;  // k tile
  int tx = threadIdx.x & 31, ty = threadIdx.x >> 5;
#pragma unroll
  for (int r = 0; r < 32; r += 8) {
    int k = j * 32 + ty + r, n = i * 32 + tx;
    tile[ty + r][tx] = (k < K && n < N) ? W[(size_t)k * N + n] : 0.0f;
  }
  __syncthreads();
#pragma unroll
  for (int r = 0; r < 32; r += 8) {
    int n = i * 32 + ty + r, k = j * 32 + tx;
    Wt[(size_t)n * Kpad + k] = (bf16_t)tile[tx][ty + r];
  }
}

// ---- async 16B global->LDS (wave-uniform base + lane*16 layout) ----
__device__ __forceinline__ void stage16(const bf16_t* gp, bf16_t* lp) {
  __builtin_amdgcn_global_load_lds((__attribute__((address_space(1))) void*)gp,
                                   (__attribute__((address_space(3))) void*)lp,
                                   16, 0, 0);
}

// ---- bf16 MFMA GEMM, 128x128 tile, BK=32, raw bf16 out (no bias/act) ----
// A [8192,K] row-major bf16 (32|K), Bt [2432,K] row-major bf16.
// G[row,col] = A@Bt^T, coalesced stores via LDS transpose.
__global__ __launch_bounds__(256) void gemm_raw(const bf16_t* __restrict__ A,
                                                const bf16_t* __restrict__ Bt,
                                                bf16_t* __restrict__ G,
                                                int K) {
  __shared__ __align__(16) bf16_t S[8192];  // As[0:4096) Bs[4096:8192)
  bf16_t* As = S;
  bf16_t* Bs = S + 4096;
  const int tid = threadIdx.x;
  const int wave = tid >> 6, lane = tid & 63;
  const int wm = wave >> 1, wn = wave & 1;  // 2x2 waves of 64x64
  const int mBase = blockIdx.y * 128;
  const int nBase = blockIdx.x * 128;

  const int rowA = tid >> 2, cq = tid & 3;  // 16B chunk per thread
  const size_t aOff0 = (size_t)(mBase + rowA) * K + cq * 8;
  const size_t aOff1 = (size_t)(mBase + 64 + rowA) * K + cq * 8;
  const size_t bOff0 = (size_t)(nBase + rowA) * K + cq * 8;
  const size_t bOff1 = (size_t)(nBase + 64 + rowA) * K + cq * 8;

  f32x4 acc[4][4];
#pragma unroll
  for (int mt = 0; mt < 4; ++mt)
#pragma unroll
    for (int nt = 0; nt < 4; ++nt) {
      f32x4 z = {0.0f, 0.0f, 0.0f, 0.0f};
      acc[mt][nt] = z;
    }

  const int fr = lane & 15, fq = lane >> 4;

  for (int k0 = 0; k0 < K; k0 += 32) {
    stage16(A + aOff0 + k0, &As[tid * 8]);
    stage16(A + aOff1 + k0, &As[2048 + tid * 8]);
    stage16(Bt + bOff0 + k0, &Bs[tid * 8]);
    stage16(Bt + bOff1 + k0, &Bs[2048 + tid * 8]);
    __syncthreads();

    bf16x8 af[4], bfv[4];
#pragma unroll
    for (int mt = 0; mt < 4; ++mt)
      af[mt] = *(const bf16x8*)&As[(wm * 64 + mt * 16 + fr) * 32 + fq * 8];
#pragma unroll
    for (int nt = 0; nt < 4; ++nt)
      bfv[nt] = *(const bf16x8*)&Bs[(wn * 64 + nt * 16 + fr) * 32 + fq * 8];
#pragma unroll
    for (int mt = 0; mt < 4; ++mt)
#pragma unroll
      for (int nt = 0; nt < 4; ++nt)
        acc[mt][nt] = __builtin_amdgcn_mfma_f32_16x16x32_bf16(
            af[mt], bfv[nt], acc[mt][nt], 0, 0, 0);
    __syncthreads();
  }

  // epilogue: C/D layout col=lane&15, row=(lane>>4)*4+r. Transpose each
  // mt-slab (32 rows x 128 cols) through LDS (row pad -> stride 136) and
  // store as 2x16B coalesced vectors per thread.
  bf16_t* Et = S;  // reuse staging LDS (needs 32*136*2 = 8704 B)
  const int erow = tid >> 3;          // 0..31
  const int ecol = (tid & 7) * 16;    // 0..112
  const int ewm = erow >> 4, er = erow & 15;
#pragma unroll
  for (int mt = 0; mt < 4; ++mt) {
    __syncthreads();
#pragma unroll
    for (int nt = 0; nt < 4; ++nt)
#pragma unroll
      for (int r = 0; r < 4; ++r)
        Et[(wm * 16 + fq * 4 + r) * 136 + wn * 64 + nt * 16 + fr] =
            (bf16_t)acc[mt][nt][r];
    __syncthreads();
    const int grow = mBase + ewm * 64 + mt * 16 + er;
    bf16_t* dst = &G[(size_t)grow * LDG + nBase + ecol];
    *(bf16x8*)dst = *(const bf16x8*)&Et[erow * 136 + ecol];
    *(bf16x8*)(dst + 8) = *(const bf16x8*)&Et[erow * 136 + ecol + 8];
  }
}

// ---- segment-parallel fo-pool scan over one T-chunk ----
// G bf16 RAW gates: z' at col h, f' at h+800, o' at h+1600 (pre-bias/act).
// Thread (chain, seg): seg handles 16 timesteps. c_t = a_t c_{t-1} + b_t with
// a=1-f, b=f*z, f=sigmoid(f'+bf), z=tanh(z'+bz). Phase 1: activate + compose
// (A,B) per segment (gates kept in registers). Phase 2: 32 serial combiners
// per block via LDS. Phase 3: rescan, h_t = sigmoid(o'+bo) * c_t.
__global__ __launch_bounds__(256) void scan_chunk_seg(
    const bf16_t* __restrict__ G, const float* __restrict__ bias,
    bf16_t* __restrict__ Hout, float* __restrict__ carry,
    float* __restrict__ outC, int outOff, int writeH, int first, int last) {
  __shared__ float SA[8][32], SB[8][32], SC[8][32];
  const int chainLane = threadIdx.x & 31;
  const int seg = threadIdx.x >> 5;
  const int ch = blockIdx.x * 32 + chainLane;  // 0..51199
  const int b = ch / HID, h = ch - b * HID;
  const int t0 = seg * 16;
  const float bz = bias[h], bf = bias[h + 800];
  const float bo = writeH ? bias[h + 1600] : 0.0f;

  float zr[16], fv[16];
#pragma unroll
  for (int j = 0; j < 16; ++j) {
    size_t base = (size_t)((t0 + j) * BATCH + b) * LDG + h;
    zr[j] = fast_tanh((float)G[base] + bz);
    fv[j] = fast_sigmoid((float)G[base + 800] + bf);
  }
  float A = 1.0f, Bacc = 0.0f;
#pragma unroll
  for (int j = 0; j < 16; ++j) {
    const float a = 1.0f - fv[j];
    A *= a;
    Bacc = fmaf(a, Bacc, fv[j] * zr[j]);
  }
  SA[seg][chainLane] = A;
  SB[seg][chainLane] = Bacc;
  __syncthreads();
  if (threadIdx.x < 32) {
    const int cc = blockIdx.x * 32 + threadIdx.x;
    float c = first ? 0.0f : carry[cc];
#pragma unroll
    for (int s = 0; s < 8; ++s) {
      SC[s][threadIdx.x] = c;
      c = fmaf(SA[s][threadIdx.x], c, SB[s][threadIdx.x]);
    }
    carry[cc] = c;
    if (last) {
      const int b2 = cc / HID, h2 = cc - b2 * HID;
      outC[b2 * 2400 + outOff + h2] = c;
    }
  }
  __syncthreads();
  if (!writeH) return;
  float c = SC[seg][chainLane];
#pragma unroll
  for (int j = 0; j < 16; ++j) {
    const size_t row = (size_t)((t0 + j) * BATCH + b);
    const float o = fast_sigmoid((float)G[row * LDG + h + 1600] + bo);
    c = fmaf(fv[j], zr[j] - c, c);  // f*z + (1-f)*c
    Hout[row * HID + h] = (bf16_t)(o * c);
  }
}

extern "C" void kernel_launch(void* const* d_in, const int* in_sizes, int n_in,
                              void* d_out, int out_size, void* d_ws, size_t ws_size,
                              hipStream_t stream) {
  const float* sent = (const float*)d_in[0];
  // d_in[1] = lengths: unused by the reference
  const float* W0 = (const float*)d_in[2];
  const float* b0 = (const float*)d_in[3];
  const float* W1 = (const float*)d_in[4];
  const float* b1 = (const float*)d_in[5];
  const float* W2 = (const float*)d_in[6];
  const float* b2 = (const float*)d_in[7];
  float* out = (float*)d_out;

  char* ws = (char*)d_ws;
  size_t off = 0;
  auto alloc = [&](size_t bytes) {
    void* p = ws + off;
    off += (bytes + 255) & ~(size_t)255;
    return p;
  };
  bf16_t* W0t = (bf16_t*)alloc((size_t)2432 * 320 * 2);  // 1.6 MB
  bf16_t* W1t = (bf16_t*)alloc((size_t)2432 * 800 * 2);  // 3.9 MB
  bf16_t* W2t = (bf16_t*)alloc((size_t)2432 * 800 * 2);  // 3.9 MB
  bf16_t* A0c = (bf16_t*)alloc((size_t)MC * 320 * 2);    // 5.2 MB
  bf16_t* H0c = (bf16_t*)alloc((size_t)MC * HID * 2);    // 13.1 MB
  bf16_t* H1c = (bf16_t*)alloc((size_t)MC * HID * 2);    // 13.1 MB
  bf16_t* ZFO = (bf16_t*)alloc((size_t)MC * LDG * 2);    // 39.8 MB
  float* C0 = (float*)alloc((size_t)BATCH * HID * 4);    // 205 KB
  float* C1 = (float*)alloc((size_t)BATCH * HID * 4);
  float* C2 = (float*)alloc((size_t)BATCH * HID * 4);
  if (off > ws_size) return;  // ws too small: fail verification, don't fault

  transpose_cast_w<<<dim3(76, 10), 256, 0, stream>>>(W0, W0t, 300, 2400, 320);
  transpose_cast_w<<<dim3(76, 25), 256, 0, stream>>>(W1, W1t, 800, 2400, 800);
  transpose_cast_w<<<dim3(76, 25), 256, 0, stream>>>(W2, W2t, 800, 2400, 800);

  for (int c = 0; c < NCHUNK; ++c) {
    const int first = (c == 0), last = (c == NCHUNK - 1);
    // layer 0
    cast_pad_a0<<<(MC * 320 + 255) / 256, 256, 0, stream>>>(
        sent + (size_t)c * MC * EMB, A0c);
    gemm_raw<<<dim3(19, 64), 256, 0, stream>>>(A0c, W0t, ZFO, 320);
    scan_chunk_seg<<<1600, 256, 0, stream>>>(ZFO, b0, H0c, C0, out, 0, 1, first, last);
    // layer 1
    gemm_raw<<<dim3(19, 64), 256, 0, stream>>>(H0c, W1t, ZFO, 800);
    scan_chunk_seg<<<1600, 256, 0, stream>>>(ZFO, b1, H1c, C1, out, 800, 1, first, last);
    // layer 2: o-gate dead (only c_last needed) -> 13 col tiles (N=1664)
    gemm_raw<<<dim3(13, 64), 256, 0, stream>>>(H1c, W2t, ZFO, 800);
    scan_chunk_seg<<<1600, 256, 0, stream>>>(ZFO, b2, nullptr, C2, out, 1600, 0, first, last);
  }
}

// Round 5
// 852.822 us; speedup vs baseline: 1.9254x; 1.0314x over previous
//
#include <hip/hip_runtime.h>
#include <hip/hip_bf16.h>
#include <cstdint>
#include <cstddef>

// QRNN encoder, 3 layers. T=512 B=64 E=300 H=800.
// Chunked pipeline (4 chunks of T_C=128): per chunk, per layer:
//   bf16 MFMA GEMM (BK=64, raw bf16 gates out, 2-barrier LDS-transpose
//   epilogue) -> segment-parallel fo-pool scan (z,f column-interleaved for
//   dword gate loads; bias+activation fp32 in scan) -> h chunk (bf16, LD 832).
// Gate column layout: cols [0,1600) = z,f interleaved (z at 2h, f at 2h+1),
// cols [1600,2400) = o at 1600+h, rest pad. Layer 2 drops o (N=1664).
// Workspace ~82 MB.

typedef __bf16 bf16_t;
typedef __bf16 bf16x8 __attribute__((ext_vector_type(8)));
typedef float f32x4 __attribute__((ext_vector_type(4)));

#define T_SEQ 512
#define T_C 128
#define NCHUNK 4
#define BATCH 64
#define EMB 300
#define HID 800
#define LDH 832                 // h buffer leading dim (K padded for BK=64)
#define MC (T_C * BATCH)        // 8192 rows per chunk

__device__ __forceinline__ float fast_sigmoid(float x) {
  return 1.0f / (1.0f + __expf(-x));
}
__device__ __forceinline__ float fast_tanh(float x) {
  return 2.0f / (1.0f + __expf(-2.0f * x)) - 1.0f;
}
__device__ __forceinline__ float b2f(uint32_t u) {
  union { uint32_t i; float f; } x;
  x.i = u << 16;
  return x.f;
}

// ---- prep: cast sent chunk [8192,300] fp32 -> bf16 [8192,320] (zero-pad K) ----
__global__ __launch_bounds__(256) void cast_pad_a0(const float* __restrict__ X,
                                                   bf16_t* __restrict__ Y) {
  int idx = blockIdx.x * 256 + threadIdx.x;
  if (idx >= MC * 320) return;
  int r = idx / 320, c = idx - r * 320;
  float v = (c < EMB) ? X[(size_t)r * EMB + c] : 0.0f;
  Y[idx] = (bf16_t)v;
}

// ---- prep: all 3 weights: W [K,2400] fp32 -> Wt [Npad,Kpad] bf16, with
// output-row permutation n' = 2h+g for z/f (g=0,1), o kept at 1600+h. ----
__global__ __launch_bounds__(256) void transpose_cast_w3(
    const float* __restrict__ W0, const float* __restrict__ W1,
    const float* __restrict__ W2, bf16_t* __restrict__ T0,
    bf16_t* __restrict__ T1, bf16_t* __restrict__ T2) {
  const int z = blockIdx.z;
  const float* W = z == 0 ? W0 : (z == 1 ? W1 : W2);
  bf16_t* Wt = z == 0 ? T0 : (z == 1 ? T1 : T2);
  const int K = z == 0 ? 300 : 800;
  const int Kpad = z == 0 ? 320 : 832;
  const int Npad = z == 2 ? 1664 : 2432;
  const int hasO = (z != 2);
  const int i = blockIdx.x, j = blockIdx.y;
  if (i * 32 >= Npad || j * 32 >= Kpad) return;
  __shared__ float tile[32][33];
  const int tx = threadIdx.x & 31, ty = threadIdx.x >> 5;
#pragma unroll
  for (int r = 0; r < 32; r += 8) {
    const int k = j * 32 + ty + r;
    const int np = i * 32 + tx;
    int src = 0;
    bool valid = (k < K);
    if (np < 1600) src = (np & 1) * 800 + (np >> 1);
    else if (hasO && np < 2400) src = np;
    else valid = false;
    tile[ty + r][tx] = valid ? W[(size_t)k * 2400 + src] : 0.0f;
  }
  __syncthreads();
#pragma unroll
  for (int r = 0; r < 32; r += 8) {
    const int np = i * 32 + ty + r, k = j * 32 + tx;
    if (np < Npad && k < Kpad)
      Wt[(size_t)np * Kpad + k] = (bf16_t)tile[tx][ty + r];
  }
}

// ---- async 16B global->LDS (wave-uniform base + lane*16 layout) ----
__device__ __forceinline__ void stage16(const bf16_t* gp, bf16_t* lp) {
  __builtin_amdgcn_global_load_lds((__attribute__((address_space(1))) void*)gp,
                                   (__attribute__((address_space(3))) void*)lp,
                                   16, 0, 0);
}

// ---- bf16 MFMA GEMM, 128x128 tile, BK=64, raw bf16 out (no bias/act) ----
// A [8192,K] row-major bf16 (64|K), Bt [Npad,K] row-major bf16.
// G[row,col] = A@Bt^T; all-mt LDS-transpose epilogue, 2 barriers.
__global__ __launch_bounds__(256, 3) void gemm_raw(const bf16_t* __restrict__ A,
                                                   const bf16_t* __restrict__ Bt,
                                                   bf16_t* __restrict__ G,
                                                   int K, int ldg) {
  __shared__ __align__(16) bf16_t S[17408];  // staging 16384 el; Et 17408 el
  bf16_t* As = S;          // [128][64]
  bf16_t* Bs = S + 8192;   // [128][64]
  const int tid = threadIdx.x;
  const int wave = tid >> 6, lane = tid & 63;
  const int wm = wave >> 1, wn = wave & 1;  // 2x2 waves of 64x64
  const int mBase = blockIdx.y * 128;
  const int nBase = blockIdx.x * 128;

  // staging: per matrix, 4 passes: row = (tid>>3)+32p, col-chunk = (tid&7)*8
  const int srow = tid >> 3;
  const int scol = (tid & 7) * 8;
  const size_t aBase = (size_t)(mBase + srow) * K + scol;
  const size_t bBase = (size_t)(nBase + srow) * K + scol;
  const int ldsOff = srow * 64 + scol;  // == tid*8 elements (wave-uniform+lane*16B)

  f32x4 acc[4][4];
#pragma unroll
  for (int mt = 0; mt < 4; ++mt)
#pragma unroll
    for (int nt = 0; nt < 4; ++nt) {
      f32x4 zz = {0.0f, 0.0f, 0.0f, 0.0f};
      acc[mt][nt] = zz;
    }

  const int fr = lane & 15, fq = lane >> 4;

  for (int k0 = 0; k0 < K; k0 += 64) {
#pragma unroll
    for (int p = 0; p < 4; ++p)
      stage16(A + aBase + (size_t)(32 * p) * K + k0, &As[ldsOff + p * 2048]);
#pragma unroll
    for (int p = 0; p < 4; ++p)
      stage16(Bt + bBase + (size_t)(32 * p) * K + k0, &Bs[ldsOff + p * 2048]);
    __syncthreads();
#pragma unroll
    for (int kh = 0; kh < 2; ++kh) {
      bf16x8 af[4], bfv[4];
#pragma unroll
      for (int mt = 0; mt < 4; ++mt)
        af[mt] = *(const bf16x8*)&As[(wm * 64 + mt * 16 + fr) * 64 + kh * 32 + fq * 8];
#pragma unroll
      for (int nt = 0; nt < 4; ++nt)
        bfv[nt] = *(const bf16x8*)&Bs[(wn * 64 + nt * 16 + fr) * 64 + kh * 32 + fq * 8];
#pragma unroll
      for (int mt = 0; mt < 4; ++mt)
#pragma unroll
        for (int nt = 0; nt < 4; ++nt)
          acc[mt][nt] = __builtin_amdgcn_mfma_f32_16x16x32_bf16(
              af[mt], bfv[nt], acc[mt][nt], 0, 0, 0);
    }
    __syncthreads();
  }

  // epilogue: C/D layout col=lane&15, row=(lane>>4)*4+r. Full-tile LDS
  // transpose (Et[128][136]) then 128B/thread coalesced vector stores.
  bf16_t* Et = S;
#pragma unroll
  for (int mt = 0; mt < 4; ++mt)
#pragma unroll
    for (int nt = 0; nt < 4; ++nt)
#pragma unroll
      for (int r = 0; r < 4; ++r)
        Et[(wm * 64 + mt * 16 + fq * 4 + r) * 136 + wn * 64 + nt * 16 + fr] =
            (bf16_t)acc[mt][nt][r];
  __syncthreads();
  const int q = tid & 3, r0 = tid >> 2;  // quarter-row units (64B each)
#pragma unroll
  for (int hh = 0; hh < 2; ++hh) {
    const int row = r0 + hh * 64;
    const bf16_t* src = &Et[row * 136 + q * 32];
    bf16_t* dst = &G[(size_t)(mBase + row) * ldg + nBase + q * 32];
    *(bf16x8*)dst = *(const bf16x8*)src;
    *(bf16x8*)(dst + 8) = *(const bf16x8*)(src + 8);
    *(bf16x8*)(dst + 16) = *(const bf16x8*)(src + 16);
    *(bf16x8*)(dst + 24) = *(const bf16x8*)(src + 24);
  }
}

// ---- segment-parallel fo-pool scan over one T-chunk ----
// G bf16 RAW gates, zf-interleaved: z' at col 2h, f' at 2h+1, o' at 1600+h.
// Thread (chain, seg): 16 timesteps. Phase 1: dword (z,f) loads + activate +
// compose affine (A,B). Phase 2: 32 serial combiners via LDS. Phase 3:
// rescan, h_t = sigmoid(o'+bo)*c_t into Hout[row][h] (LD 832, pad zeroed).
__global__ __launch_bounds__(256) void scan_chunk_seg(
    const bf16_t* __restrict__ G, const float* __restrict__ bias,
    bf16_t* __restrict__ Hout, float* __restrict__ carry,
    float* __restrict__ outC, int ldg, int outOff, int writeH, int first,
    int last) {
  __shared__ float SA[8][32], SB[8][32], SC[8][32];
  const int chainLane = threadIdx.x & 31;
  const int seg = threadIdx.x >> 5;
  const int ch = blockIdx.x * 32 + chainLane;  // 0..51199
  const int b = ch / HID, h = ch - b * HID;
  const int t0 = seg * 16;
  const float bz = bias[h], bf = bias[h + 800];
  const float bo = writeH ? bias[h + 1600] : 0.0f;
  const int ldgh = ldg >> 1;
  const uint32_t* Gp = (const uint32_t*)G;

  float zr[16], fv[16];
#pragma unroll
  for (int j = 0; j < 16; ++j) {
    const uint32_t v = Gp[(size_t)((t0 + j) * BATCH + b) * ldgh + h];
    zr[j] = fast_tanh(b2f(v & 0xffffu) + bz);
    fv[j] = fast_sigmoid(b2f(v >> 16) + bf);
  }
  float A = 1.0f, Bacc = 0.0f;
#pragma unroll
  for (int j = 0; j < 16; ++j) {
    const float a = 1.0f - fv[j];
    A *= a;
    Bacc = fmaf(a, Bacc, fv[j] * zr[j]);
  }
  SA[seg][chainLane] = A;
  SB[seg][chainLane] = Bacc;
  __syncthreads();
  if (threadIdx.x < 32) {
    const int cc = blockIdx.x * 32 + threadIdx.x;
    float c = first ? 0.0f : carry[cc];
#pragma unroll
    for (int s = 0; s < 8; ++s) {
      SC[s][threadIdx.x] = c;
      c = fmaf(SA[s][threadIdx.x], c, SB[s][threadIdx.x]);
    }
    carry[cc] = c;
    if (last) {
      const int b2 = cc / HID, h2 = cc - b2 * HID;
      outC[b2 * 2400 + outOff + h2] = c;
    }
  }
  __syncthreads();
  if (!writeH) return;
  float c = SC[seg][chainLane];
#pragma unroll
  for (int j = 0; j < 16; ++j) {
    const size_t row = (size_t)((t0 + j) * BATCH + b);
    const float o = fast_sigmoid((float)G[row * ldg + 1600 + h] + bo);
    c = fmaf(fv[j], zr[j] - c, c);  // f*z + (1-f)*c
    Hout[row * LDH + h] = (bf16_t)(o * c);
    if (h >= 768) Hout[row * LDH + h + 32] = (bf16_t)0.0f;  // zero K-pad cols
  }
}

extern "C" void kernel_launch(void* const* d_in, const int* in_sizes, int n_in,
                              void* d_out, int out_size, void* d_ws, size_t ws_size,
                              hipStream_t stream) {
  const float* sent = (const float*)d_in[0];
  // d_in[1] = lengths: unused by the reference
  const float* W0 = (const float*)d_in[2];
  const float* b0 = (const float*)d_in[3];
  const float* W1 = (const float*)d_in[4];
  const float* b1 = (const float*)d_in[5];
  const float* W2 = (const float*)d_in[6];
  const float* b2 = (const float*)d_in[7];
  float* out = (float*)d_out;

  char* ws = (char*)d_ws;
  size_t off = 0;
  auto alloc = [&](size_t bytes) {
    void* p = ws + off;
    off += (bytes + 255) & ~(size_t)255;
    return p;
  };
  bf16_t* W0t = (bf16_t*)alloc((size_t)2432 * 320 * 2);  // 1.6 MB
  bf16_t* W1t = (bf16_t*)alloc((size_t)2432 * 832 * 2);  // 4.0 MB
  bf16_t* W2t = (bf16_t*)alloc((size_t)1664 * 832 * 2);  // 2.8 MB
  bf16_t* A0c = (bf16_t*)alloc((size_t)MC * 320 * 2);    // 5.2 MB
  bf16_t* H0c = (bf16_t*)alloc((size_t)MC * LDH * 2);    // 13.6 MB
  bf16_t* H1c = (bf16_t*)alloc((size_t)MC * LDH * 2);    // 13.6 MB
  bf16_t* ZFO = (bf16_t*)alloc((size_t)MC * 2432 * 2);   // 39.8 MB
  float* C0 = (float*)alloc((size_t)BATCH * HID * 4);    // 205 KB
  float* C1 = (float*)alloc((size_t)BATCH * HID * 4);
  float* C2 = (float*)alloc((size_t)BATCH * HID * 4);
  if (off > ws_size) return;  // ws too small: fail verification, don't fault

  transpose_cast_w3<<<dim3(76, 26, 3), 256, 0, stream>>>(W0, W1, W2, W0t, W1t, W2t);

  for (int c = 0; c < NCHUNK; ++c) {
    const int first = (c == 0), last = (c == NCHUNK - 1);
    // layer 0 (K=320)
    cast_pad_a0<<<(MC * 320 + 255) / 256, 256, 0, stream>>>(
        sent + (size_t)c * MC * EMB, A0c);
    gemm_raw<<<dim3(19, 64), 256, 0, stream>>>(A0c, W0t, ZFO, 320, 2432);
    scan_chunk_seg<<<1600, 256, 0, stream>>>(ZFO, b0, H0c, C0, out, 2432, 0, 1,
                                             first, last);
    // layer 1 (K=832 padded)
    gemm_raw<<<dim3(19, 64), 256, 0, stream>>>(H0c, W1t, ZFO, 832, 2432);
    scan_chunk_seg<<<1600, 256, 0, stream>>>(ZFO, b1, H1c, C1, out, 2432, 800,
                                             1, first, last);
    // layer 2: o-gate dead -> N=1664 (z,f only)
    gemm_raw<<<dim3(13, 64), 256, 0, stream>>>(H1c, W2t, ZFO, 832, 1664);
    scan_chunk_seg<<<1600, 256, 0, stream>>>(ZFO, b2, nullptr, C2, out, 1664,
                                             1600, 0, first, last);
  }
}

// Round 6
// 751.831 us; speedup vs baseline: 2.1840x; 1.1343x over previous
//
#include <hip/hip_runtime.h>
#include <hip/hip_bf16.h>
#include <cstdint>
#include <cstddef>

// QRNN encoder, 3 layers. T=512 B=64 E=300 H=800.
// Chunked pipeline (4 chunks of T_C=128): per chunk, per layer:
//   bf16 MFMA GEMM (BK=64, XOR-swizzled LDS staging to kill bank conflicts,
//   XCD-aware block swizzle for A-tile L2 locality, raw bf16 gates out,
//   2-barrier LDS-transpose epilogue) -> segment-parallel fo-pool scan
//   (z,f column-interleaved; bias+activation fp32 in scan) -> h chunk.
// Gate column layout: cols [0,1600) = z,f interleaved (z at 2h, f at 2h+1),
// cols [1600,2400) = o at 1600+h, rest pad. Layer 2 drops o (N=1664).
// Workspace ~82 MB.

typedef __bf16 bf16_t;
typedef __bf16 bf16x8 __attribute__((ext_vector_type(8)));
typedef float f32x4 __attribute__((ext_vector_type(4)));

#define T_SEQ 512
#define T_C 128
#define NCHUNK 4
#define BATCH 64
#define EMB 300
#define HID 800
#define LDH 832                 // h buffer leading dim (K padded for BK=64)
#define MC (T_C * BATCH)        // 8192 rows per chunk

__device__ __forceinline__ float fast_sigmoid(float x) {
  return 1.0f / (1.0f + __expf(-x));
}
__device__ __forceinline__ float fast_tanh(float x) {
  return 2.0f / (1.0f + __expf(-2.0f * x)) - 1.0f;
}
__device__ __forceinline__ float b2f(uint32_t u) {
  union { uint32_t i; float f; } x;
  x.i = u << 16;
  return x.f;
}

// ---- prep: cast sent chunk [8192,300] fp32 -> bf16 [8192,320] (zero-pad K) ----
__global__ __launch_bounds__(256) void cast_pad_a0(const float* __restrict__ X,
                                                   bf16_t* __restrict__ Y) {
  int idx = blockIdx.x * 256 + threadIdx.x;
  if (idx >= MC * 320) return;
  int r = idx / 320, c = idx - r * 320;
  float v = (c < EMB) ? X[(size_t)r * EMB + c] : 0.0f;
  Y[idx] = (bf16_t)v;
}

// ---- prep: all 3 weights: W [K,2400] fp32 -> Wt [Npad,Kpad] bf16, with
// output-row permutation n' = 2h+g for z/f (g=0,1), o kept at 1600+h. ----
__global__ __launch_bounds__(256) void transpose_cast_w3(
    const float* __restrict__ W0, const float* __restrict__ W1,
    const float* __restrict__ W2, bf16_t* __restrict__ T0,
    bf16_t* __restrict__ T1, bf16_t* __restrict__ T2) {
  const int z = blockIdx.z;
  const float* W = z == 0 ? W0 : (z == 1 ? W1 : W2);
  bf16_t* Wt = z == 0 ? T0 : (z == 1 ? T1 : T2);
  const int K = z == 0 ? 300 : 800;
  const int Kpad = z == 0 ? 320 : 832;
  const int Npad = z == 2 ? 1664 : 2432;
  const int hasO = (z != 2);
  const int i = blockIdx.x, j = blockIdx.y;
  if (i * 32 >= Npad || j * 32 >= Kpad) return;
  __shared__ float tile[32][33];
  const int tx = threadIdx.x & 31, ty = threadIdx.x >> 5;
#pragma unroll
  for (int r = 0; r < 32; r += 8) {
    const int k = j * 32 + ty + r;
    const int np = i * 32 + tx;
    int src = 0;
    bool valid = (k < K);
    if (np < 1600) src = (np & 1) * 800 + (np >> 1);
    else if (hasO && np < 2400) src = np;
    else valid = false;
    tile[ty + r][tx] = valid ? W[(size_t)k * 2400 + src] : 0.0f;
  }
  __syncthreads();
#pragma unroll
  for (int r = 0; r < 32; r += 8) {
    const int np = i * 32 + ty + r, k = j * 32 + tx;
    if (np < Npad && k < Kpad)
      Wt[(size_t)np * Kpad + k] = (bf16_t)tile[tx][ty + r];
  }
}

// ---- async 16B global->LDS (wave-uniform base + lane*16 layout) ----
__device__ __forceinline__ void stage16(const bf16_t* gp, bf16_t* lp) {
  __builtin_amdgcn_global_load_lds((__attribute__((address_space(1))) void*)gp,
                                   (__attribute__((address_space(3))) void*)lp,
                                   16, 0, 0);
}

// ---- bf16 MFMA GEMM, 128x128 tile, BK=64, raw bf16 out (no bias/act) ----
// A [8192,K] row-major bf16 (64|K), Bt [Npad,K] row-major bf16.
// LDS staging XOR-swizzled: row r, LDS chunk c holds global chunk c^(r&7)
// (16B chunks), so ds_read_b128 fragment reads spread across all banks.
// XCD swizzle: linear block L -> XCD x=L%8 owns m-tiles [8x,8x+8).
__global__ __launch_bounds__(256, 3) void gemm_raw(const bf16_t* __restrict__ A,
                                                   const bf16_t* __restrict__ Bt,
                                                   bf16_t* __restrict__ G,
                                                   int K, int ldg) {
  __shared__ __align__(16) bf16_t S[17920];  // staging 16384 el; Et 128*140
  bf16_t* As = S;          // [128][64] swizzled
  bf16_t* Bs = S + 8192;   // [128][64] swizzled
  const int tid = threadIdx.x;
  const int wave = tid >> 6, lane = tid & 63;
  const int wm = wave >> 1, wn = wave & 1;  // 2x2 waves of 64x64
  // XCD-aware remap: L%8 = XCD gets 8 consecutive m-tiles, all n-tiles.
  const int nT = gridDim.x;
  const int L = blockIdx.y * nT + blockIdx.x;
  const int xcd = L & 7, j = L >> 3;
  const int mBase = (xcd * 8 + j / nT) * 128;
  const int nBase = (j % nT) * 128;

  // staging: per matrix, 4 passes: row = (tid>>3)+32p, LDS chunk = tid&7,
  // global chunk = (tid&7) ^ (row&7). (row&7 invariant under +32p.)
  const int srow = tid >> 3;
  const int scolSw = ((tid & 7) ^ (srow & 7)) * 8;
  const size_t aBase = (size_t)(mBase + srow) * K + scolSw;
  const size_t bBase = (size_t)(nBase + srow) * K + scolSw;
  const int ldsOff = tid * 8;

  f32x4 acc[4][4];
#pragma unroll
  for (int mt = 0; mt < 4; ++mt)
#pragma unroll
    for (int nt = 0; nt < 4; ++nt) {
      f32x4 zz = {0.0f, 0.0f, 0.0f, 0.0f};
      acc[mt][nt] = zz;
    }

  const int fr = lane & 15, fq = lane >> 4;
  const int x0 = fr & 7;
  // LDS element offset of global chunk (kh*4+fq) in a row, post-swizzle:
  const int ckEl0 = ((0 * 4 + fq) ^ x0) * 8;
  const int ckEl1 = ((1 * 4 + fq) ^ x0) * 8;

  for (int k0 = 0; k0 < K; k0 += 64) {
#pragma unroll
    for (int p = 0; p < 4; ++p)
      stage16(A + aBase + (size_t)(32 * p) * K + k0, &As[ldsOff + p * 2048]);
#pragma unroll
    for (int p = 0; p < 4; ++p)
      stage16(Bt + bBase + (size_t)(32 * p) * K + k0, &Bs[ldsOff + p * 2048]);
    __syncthreads();
#pragma unroll
    for (int kh = 0; kh < 2; ++kh) {
      const int ck = kh ? ckEl1 : ckEl0;
      bf16x8 af[4], bfv[4];
#pragma unroll
      for (int mt = 0; mt < 4; ++mt)
        af[mt] = *(const bf16x8*)&As[(wm * 64 + mt * 16 + fr) * 64 + ck];
#pragma unroll
      for (int nt = 0; nt < 4; ++nt)
        bfv[nt] = *(const bf16x8*)&Bs[(wn * 64 + nt * 16 + fr) * 64 + ck];
#pragma unroll
      for (int mt = 0; mt < 4; ++mt)
#pragma unroll
        for (int nt = 0; nt < 4; ++nt)
          acc[mt][nt] = __builtin_amdgcn_mfma_f32_16x16x32_bf16(
              af[mt], bfv[nt], acc[mt][nt], 0, 0, 0);
    }
    __syncthreads();
  }

  // epilogue: C/D layout col=lane&15, row=(lane>>4)*4+r. Full-tile LDS
  // transpose (Et[128][140]) then 128B/thread coalesced vector stores.
  bf16_t* Et = S;
#pragma unroll
  for (int mt = 0; mt < 4; ++mt)
#pragma unroll
    for (int nt = 0; nt < 4; ++nt)
#pragma unroll
      for (int r = 0; r < 4; ++r)
        Et[(wm * 64 + mt * 16 + fq * 4 + r) * 140 + wn * 64 + nt * 16 + fr] =
            (bf16_t)acc[mt][nt][r];
  __syncthreads();
  const int q = tid & 3, r0 = tid >> 2;  // quarter-row units (64B each)
#pragma unroll
  for (int hh = 0; hh < 2; ++hh) {
    const int row = r0 + hh * 64;
    const bf16_t* src = &Et[row * 140 + q * 32];
    bf16_t* dst = &G[(size_t)(mBase + row) * ldg + nBase + q * 32];
    *(bf16x8*)dst = *(const bf16x8*)src;
    *(bf16x8*)(dst + 8) = *(const bf16x8*)(src + 8);
    *(bf16x8*)(dst + 16) = *(const bf16x8*)(src + 16);
    *(bf16x8*)(dst + 24) = *(const bf16x8*)(src + 24);
  }
}

// ---- segment-parallel fo-pool scan over one T-chunk ----
// G bf16 RAW gates, zf-interleaved: z' at col 2h, f' at 2h+1, o' at 1600+h.
// Thread (chain, seg): 16 timesteps. Phase 1: dword (z,f) loads + activate +
// compose affine (A,B). Phase 2: 32 serial combiners via LDS. Phase 3:
// rescan, h_t = sigmoid(o'+bo)*c_t into Hout[row][h] (LD 832, pad zeroed).
__global__ __launch_bounds__(256) void scan_chunk_seg(
    const bf16_t* __restrict__ G, const float* __restrict__ bias,
    bf16_t* __restrict__ Hout, float* __restrict__ carry,
    float* __restrict__ outC, int ldg, int outOff, int writeH, int first,
    int last) {
  __shared__ float SA[8][32], SB[8][32], SC[8][32];
  const int chainLane = threadIdx.x & 31;
  const int seg = threadIdx.x >> 5;
  const int ch = blockIdx.x * 32 + chainLane;  // 0..51199
  const int b = ch / HID, h = ch - b * HID;
  const int t0 = seg * 16;
  const float bz = bias[h], bf = bias[h + 800];
  const float bo = writeH ? bias[h + 1600] : 0.0f;
  const int ldgh = ldg >> 1;
  const uint32_t* Gp = (const uint32_t*)G;

  float zr[16], fv[16];
#pragma unroll
  for (int j = 0; j < 16; ++j) {
    const uint32_t v = Gp[(size_t)((t0 + j) * BATCH + b) * ldgh + h];
    zr[j] = fast_tanh(b2f(v & 0xffffu) + bz);
    fv[j] = fast_sigmoid(b2f(v >> 16) + bf);
  }
  float A = 1.0f, Bacc = 0.0f;
#pragma unroll
  for (int j = 0; j < 16; ++j) {
    const float a = 1.0f - fv[j];
    A *= a;
    Bacc = fmaf(a, Bacc, fv[j] * zr[j]);
  }
  SA[seg][chainLane] = A;
  SB[seg][chainLane] = Bacc;
  __syncthreads();
  if (threadIdx.x < 32) {
    const int cc = blockIdx.x * 32 + threadIdx.x;
    float c = first ? 0.0f : carry[cc];
#pragma unroll
    for (int s = 0; s < 8; ++s) {
      SC[s][threadIdx.x] = c;
      c = fmaf(SA[s][threadIdx.x], c, SB[s][threadIdx.x]);
    }
    carry[cc] = c;
    if (last) {
      const int b2 = cc / HID, h2 = cc - b2 * HID;
      outC[b2 * 2400 + outOff + h2] = c;
    }
  }
  __syncthreads();
  if (!writeH) return;
  float c = SC[seg][chainLane];
#pragma unroll
  for (int j = 0; j < 16; ++j) {
    const size_t row = (size_t)((t0 + j) * BATCH + b);
    const float o = fast_sigmoid((float)G[row * ldg + 1600 + h] + bo);
    c = fmaf(fv[j], zr[j] - c, c);  // f*z + (1-f)*c
    Hout[row * LDH + h] = (bf16_t)(o * c);
    if (h >= 768) Hout[row * LDH + h + 32] = (bf16_t)0.0f;  // zero K-pad cols
  }
}

extern "C" void kernel_launch(void* const* d_in, const int* in_sizes, int n_in,
                              void* d_out, int out_size, void* d_ws, size_t ws_size,
                              hipStream_t stream) {
  const float* sent = (const float*)d_in[0];
  // d_in[1] = lengths: unused by the reference
  const float* W0 = (const float*)d_in[2];
  const float* b0 = (const float*)d_in[3];
  const float* W1 = (const float*)d_in[4];
  const float* b1 = (const float*)d_in[5];
  const float* W2 = (const float*)d_in[6];
  const float* b2 = (const float*)d_in[7];
  float* out = (float*)d_out;

  char* ws = (char*)d_ws;
  size_t off = 0;
  auto alloc = [&](size_t bytes) {
    void* p = ws + off;
    off += (bytes + 255) & ~(size_t)255;
    return p;
  };
  bf16_t* W0t = (bf16_t*)alloc((size_t)2432 * 320 * 2);  // 1.6 MB
  bf16_t* W1t = (bf16_t*)alloc((size_t)2432 * 832 * 2);  // 4.0 MB
  bf16_t* W2t = (bf16_t*)alloc((size_t)1664 * 832 * 2);  // 2.8 MB
  bf16_t* A0c = (bf16_t*)alloc((size_t)MC * 320 * 2);    // 5.2 MB
  bf16_t* H0c = (bf16_t*)alloc((size_t)MC * LDH * 2);    // 13.6 MB
  bf16_t* H1c = (bf16_t*)alloc((size_t)MC * LDH * 2);    // 13.6 MB
  bf16_t* ZFO = (bf16_t*)alloc((size_t)MC * 2432 * 2);   // 39.8 MB
  float* C0 = (float*)alloc((size_t)BATCH * HID * 4);    // 205 KB
  float* C1 = (float*)alloc((size_t)BATCH * HID * 4);
  float* C2 = (float*)alloc((size_t)BATCH * HID * 4);
  if (off > ws_size) return;  // ws too small: fail verification, don't fault

  transpose_cast_w3<<<dim3(76, 26, 3), 256, 0, stream>>>(W0, W1, W2, W0t, W1t, W2t);

  for (int c = 0; c < NCHUNK; ++c) {
    const int first = (c == 0), last = (c == NCHUNK - 1);
    // layer 0 (K=320)
    cast_pad_a0<<<(MC * 320 + 255) / 256, 256, 0, stream>>>(
        sent + (size_t)c * MC * EMB, A0c);
    gemm_raw<<<dim3(19, 64), 256, 0, stream>>>(A0c, W0t, ZFO, 320, 2432);
    scan_chunk_seg<<<1600, 256, 0, stream>>>(ZFO, b0, H0c, C0, out, 2432, 0, 1,
                                             first, last);
    // layer 1 (K=832 padded)
    gemm_raw<<<dim3(19, 64), 256, 0, stream>>>(H0c, W1t, ZFO, 832, 2432);
    scan_chunk_seg<<<1600, 256, 0, stream>>>(ZFO, b1, H1c, C1, out, 2432, 800,
                                             1, first, last);
    // layer 2: o-gate dead -> N=1664 (z,f only)
    gemm_raw<<<dim3(13, 64), 256, 0, stream>>>(H1c, W2t, ZFO, 832, 1664);
    scan_chunk_seg<<<1600, 256, 0, stream>>>(ZFO, b2, nullptr, C2, out, 1664,
                                             1600, 0, first, last);
  }
}